// Round 1
// 40529.532 us; speedup vs baseline: 1.1517x; 1.1517x over previous
//
#include <hip/hip_runtime.h>

#define S_LEN 65536
#define HDIM 128

typedef _Float16 half2_t __attribute__((ext_vector_type(2)));
typedef _Float16 half8_t __attribute__((ext_vector_type(8)));
typedef float f32x4 __attribute__((ext_vector_type(4)));

__device__ __forceinline__ float sigm(float x) {
    return 1.0f / (1.0f + __expf(-x));
}
__device__ __forceinline__ float tanh_fast(float x) {
    return 2.0f / (1.0f + __expf(-2.0f * x)) - 1.0f;
}
__device__ __forceinline__ float dot2(half2_t a, half2_t b, float c) {
#if __has_builtin(__builtin_amdgcn_fdot2)
    return __builtin_amdgcn_fdot2(a, b, c, false);
#else
    return fmaf((float)a.x, (float)b.x, fmaf((float)a.y, (float)b.y, c));
#endif
}

// Raw workgroup barrier: drain LDS only (lgkmcnt), leave global loads/stores
// (x prefetch, h_hist) in flight across the barrier. __syncthreads would
// emit s_waitcnt vmcnt(0) every step and serialize the prefetch.
#define WG_BARRIER() do {                                         \
    asm volatile("s_waitcnt lgkmcnt(0)" ::: "memory");            \
    __builtin_amdgcn_s_barrier();                                 \
    asm volatile("" ::: "memory");                                \
} while (0)

// ================= Kernel 1: MFMA recurrence, gate-local waves ============
// R7: previous version was latency-bound at ~1640 cyc/step: 2 barriers + 2
// cross-wave LDS round trips (h AND the 2KiB gate vector) + implicit
// vmcnt(0) drains at each __syncthreads.
// Restructure: permute W_hh rows so wave w's 4 tiles are the {i,f,g,o} gate
// rows of h-slice [16w,16w+16). Replicate h into B-columns 0..3 (broadcast
// ds_read, free) so lane (quad,n) n<4 holds ALL FOUR gates of
// h[16w+4*quad+n] at static acc index n (3 cndmask selects per gate).
// Gates and c never touch LDS; only the 256B h vector crosses waves, in a
// ping-pong buffer with ONE raw s_barrier per step.
// Layouts (same verified mapping as previous passing kernel):
//   A[m=lane&15][k=32*cc+8*quad+j], B mirrored (n=lane&15, k=8*quad+j),
//   D col=lane&15, row=4*quad+reg.
__global__ __launch_bounds__(512)
__attribute__((amdgpu_waves_per_eu(2, 2)))
void lstm_seq_mfma(const float* __restrict__ x,
                   const float* __restrict__ h0,
                   const float* __restrict__ c0,
                   const float* __restrict__ W_ih,
                   const float* __restrict__ W_hh,
                   const float* __restrict__ b_ih,
                   const float* __restrict__ b_hh,
                   _Float16* __restrict__ h_hist)
{
    __shared__ __align__(16) _Float16 h_buf[2][HDIM];  // ping-pong h_t (f16)

    const int tid  = threadIdx.x;       // 0..511, 8 waves
    const int lane = tid & 63;
    const int w    = tid >> 6;          // wave id 0..7: h-slice [16w,16w+16)
    const int m    = lane & 15;         // A row within tile; also B/D col
    const int quad = lane >> 4;         // 0..3

    // ---- A fragments: tile i = gate i rows of this wave's h-slice ----
    // Row permutation vs previous version: row = i*128 + 16*w + m.
#define LOAD_AF(i, cc) \
    half8_t af_##i##_##cc; { \
        const float* s_ = W_hh + (size_t)((i) * 128 + w * 16 + m) * HDIM \
                               + 32 * (cc) + 8 * quad; \
        af_##i##_##cc = (half8_t){ \
            (_Float16)s_[0], (_Float16)s_[1], (_Float16)s_[2], (_Float16)s_[3], \
            (_Float16)s_[4], (_Float16)s_[5], (_Float16)s_[6], (_Float16)s_[7] }; \
        asm volatile("" : "+v"(af_##i##_##cc)); }
    LOAD_AF(0, 0) LOAD_AF(0, 1) LOAD_AF(0, 2) LOAD_AF(0, 3)
    LOAD_AF(1, 0) LOAD_AF(1, 1) LOAD_AF(1, 2) LOAD_AF(1, 3)
    LOAD_AF(2, 0) LOAD_AF(2, 1) LOAD_AF(2, 2) LOAD_AF(2, 3)
    LOAD_AF(3, 0) LOAD_AF(3, 1) LOAD_AF(3, 2) LOAD_AF(3, 3)
#undef LOAD_AF

    // ---- Worker state: lanes m<4, one h element each ----
    const bool worker = (m < 4);
    const int  hidx   = w * 16 + quad * 4 + (m & 3);   // 0..127 (workers)
    float wi00 = 0.f, wi01 = 0.f, bs0 = 0.f;
    float wi10 = 0.f, wi11 = 0.f, bs1 = 0.f;
    float wi20 = 0.f, wi21 = 0.f, bs2 = 0.f;
    float wi30 = 0.f, wi31 = 0.f, bs3 = 0.f;
    float c = 0.0f;
    if (worker) {
        const int r0 = hidx;
        const int r1 = hidx + 128;
        const int r2 = hidx + 256;
        const int r3 = hidx + 384;
        wi00 = W_ih[2 * r0]; wi01 = W_ih[2 * r0 + 1]; bs0 = b_ih[r0] + b_hh[r0];
        wi10 = W_ih[2 * r1]; wi11 = W_ih[2 * r1 + 1]; bs1 = b_ih[r1] + b_hh[r1];
        wi20 = W_ih[2 * r2]; wi21 = W_ih[2 * r2 + 1]; bs2 = b_ih[r2] + b_hh[r2];
        wi30 = W_ih[2 * r3]; wi31 = W_ih[2 * r3 + 1]; bs3 = b_ih[r3] + b_hh[r3];
        c = c0[hidx];
    }
    if (tid < HDIM) h_buf[0][tid] = (_Float16)h0[tid];
    __syncthreads();

    const float2* xp = (const float2*)x;
    float2 xcur = xp[0];                 // FIFO depth 2: covers L2 latency
    float2 xn1  = xp[1];

    const bool selod = (m & 1) != 0;
    const bool selhi = (m & 2) != 0;

#define MFMA_T(i) \
    acc##i = __builtin_amdgcn_mfma_f32_16x16x32_f16(af_##i##_0, bf0, acc##i, 0, 0, 0); \
    acc##i = __builtin_amdgcn_mfma_f32_16x16x32_f16(af_##i##_1, bf1, acc##i, 0, 0, 0); \
    acc##i = __builtin_amdgcn_mfma_f32_16x16x32_f16(af_##i##_2, bf2, acc##i, 0, 0, 0); \
    acc##i = __builtin_amdgcn_mfma_f32_16x16x32_f16(af_##i##_3, bf3, acc##i, 0, 0, 0);

#define STEP(T, RB, WB) { \
    /* B frags: all lanes read same 4 lines (broadcast) -> cols 0..15 = h */ \
    const half8_t* hb_ = (const half8_t*)(RB); \
    half8_t bf0 = hb_[quad]; \
    half8_t bf1 = hb_[4 + quad]; \
    half8_t bf2 = hb_[8 + quad]; \
    half8_t bf3 = hb_[12 + quad]; \
    f32x4 acc0 = {0.f, 0.f, 0.f, 0.f}; \
    f32x4 acc1 = acc0, acc2 = acc0, acc3 = acc0; \
    MFMA_T(0) MFMA_T(1) MFMA_T(2) MFMA_T(3) \
    int tn_ = (T) + 2; if (tn_ >= S_LEN) tn_ = S_LEN - 1; \
    float2 xnew_ = xp[tn_]; \
    const float xg0 = fmaf(wi00, xcur.x, fmaf(wi01, xcur.y, bs0)); \
    const float xg1 = fmaf(wi10, xcur.x, fmaf(wi11, xcur.y, bs1)); \
    const float xg2 = fmaf(wi20, xcur.x, fmaf(wi21, xcur.y, bs2)); \
    const float xg3 = fmaf(wi30, xcur.x, fmaf(wi31, xcur.y, bs3)); \
    if (worker) { \
        float sa_, sb_; \
        sa_ = selod ? acc0[1] : acc0[0]; sb_ = selod ? acc0[3] : acc0[2]; \
        const float g0 = (selhi ? sb_ : sa_) + xg0; \
        sa_ = selod ? acc1[1] : acc1[0]; sb_ = selod ? acc1[3] : acc1[2]; \
        const float g1 = (selhi ? sb_ : sa_) + xg1; \
        sa_ = selod ? acc2[1] : acc2[0]; sb_ = selod ? acc2[3] : acc2[2]; \
        const float g2 = (selhi ? sb_ : sa_) + xg2; \
        sa_ = selod ? acc3[1] : acc3[0]; sb_ = selod ? acc3[3] : acc3[2]; \
        const float g3 = (selhi ? sb_ : sa_) + xg3; \
        const float gi = sigm(g0); \
        const float gf = sigm(g1); \
        const float gg = tanh_fast(g2); \
        const float go = sigm(g3); \
        c = fmaf(gf, c, gi * gg); \
        const float hv_ = go * tanh_fast(c); \
        const _Float16 hf_ = (_Float16)hv_; \
        (WB)[hidx] = hf_;                       /* feeds next step B-frags */ \
        h_hist[(size_t)(T) * HDIM + hidx] = hf_; /* consumed by out_proj */ \
    } \
    xcur = xn1; xn1 = xnew_; \
    WG_BARRIER(); }

    #pragma unroll 1
    for (int t = 0; t < S_LEN; t += 2) {
        STEP(t,     h_buf[0], h_buf[1])
        STEP(t + 1, h_buf[1], h_buf[0])
    }
#undef STEP
#undef MFMA_T
}

// ================= Kernel 2: out[t] = tanh(h_t).W_out + b =================
__global__ __launch_bounds__(256)
void out_proj(const _Float16* __restrict__ h_hist,
              const float* __restrict__ W_out,
              const float* __restrict__ b_out,
              float* __restrict__ out)
{
    const int lane  = threadIdx.x & 63;
    const int gwave = (blockIdx.x * 256 + threadIdx.x) >> 6;
    const int nwave = (gridDim.x * 256) >> 6;

    const float wo0 = W_out[2 * lane + 0];
    const float wo1 = W_out[2 * lane + 1];
    const float bout = b_out[0];

    for (int t = gwave; t < S_LEN; t += nwave) {
        half2_t hv = ((const half2_t*)(h_hist + t * HDIM))[lane];
        float p = tanh_fast((float)hv.x) * wo0 + tanh_fast((float)hv.y) * wo1;
        #pragma unroll
        for (int off = 32; off > 0; off >>= 1)
            p += __shfl_xor(p, off, 64);
        if (lane == 0) out[t] = p + bout;
    }
}

// ================= Fallback: fused single kernel (ws too small) ===========
#define H_HI_OFF 144
__global__ __launch_bounds__(1024)
__attribute__((amdgpu_waves_per_eu(4, 4)))
void lstm_seq_full(const float* __restrict__ x,
                   const float* __restrict__ h0,
                   const float* __restrict__ c0,
                   const float* __restrict__ W_ih,
                   const float* __restrict__ W_hh,
                   const float* __restrict__ b_ih,
                   const float* __restrict__ b_hh,
                   const float* __restrict__ W_out,
                   const float* __restrict__ b_out,
                   float* __restrict__ out)
{
    __shared__ __align__(16) unsigned char h_raw[2 * H_HI_OFF];
    __shared__ float gates_part[2 * 512];
    __shared__ float red_sh[2];

    const int tid  = threadIdx.x;
    const int j    = tid >> 1;
    const int half = tid & 1;

    const float2* wr2 = (const float2*)(W_hh + j * HDIM + half * 64);
#define WDEF(i) half2_t W##i; { float2 t = wr2[i]; \
        W##i.x = (_Float16)t.x; W##i.y = (_Float16)t.y; } \
        asm volatile("" : "+v"(W##i));
    WDEF(0)  WDEF(1)  WDEF(2)  WDEF(3)  WDEF(4)  WDEF(5)  WDEF(6)  WDEF(7)
    WDEF(8)  WDEF(9)  WDEF(10) WDEF(11) WDEF(12) WDEF(13) WDEF(14) WDEF(15)
    WDEF(16) WDEF(17) WDEF(18) WDEF(19) WDEF(20) WDEF(21) WDEF(22) WDEF(23)
    WDEF(24) WDEF(25) WDEF(26) WDEF(27) WDEF(28) WDEF(29) WDEF(30) WDEF(31)
#undef WDEF

    float wih0 = 0.0f, wih1 = 0.0f, bias = 0.0f;
    if (half == 0) {
        wih0 = W_ih[2 * j + 0];
        wih1 = W_ih[2 * j + 1];
        bias = b_ih[j] + b_hh[j];
    }

    float c = 0.0f, wout = 0.0f;
    _Float16* hw = (_Float16*)(h_raw + ((tid < 64) ? 2 * tid
                                                   : H_HI_OFF + 2 * (tid - 64)));
    if (tid < HDIM) {
        c = c0[tid];
        wout = W_out[tid];
        *hw = (_Float16)h0[tid];
    }
    const float bout = b_out[0];
    __syncthreads();

    const float2* xp = (const float2*)x;
    float2 xcur = xp[0];
    const half8_t* hp = (const half8_t*)(h_raw + half * H_HI_OFF);

    #pragma unroll 1
    for (int t = 0; t < S_LEN; ++t) {
        const int tn = (t + 1 < S_LEN) ? (t + 1) : (S_LEN - 1);
        float2 xnext = xp[tn];

        float a0 = fmaf(wih0, xcur.x, fmaf(wih1, xcur.y, bias));
        float a1 = 0.0f, a2 = 0.0f, a3 = 0.0f;

#define CHUNK(cc, w0_, w1_, w2_, w3_) {                         \
        half8_t hv = hp[cc];                                    \
        half2_t p0 = { hv[0], hv[1] };                          \
        half2_t p1 = { hv[2], hv[3] };                          \
        half2_t p2 = { hv[4], hv[5] };                          \
        half2_t p3 = { hv[6], hv[7] };                          \
        a0 = dot2(w0_, p0, a0);                                 \
        a1 = dot2(w1_, p1, a1);                                 \
        a2 = dot2(w2_, p2, a2);                                 \
        a3 = dot2(w3_, p3, a3); }
        CHUNK(0, W0,  W1,  W2,  W3)
        CHUNK(1, W4,  W5,  W6,  W7)
        CHUNK(2, W8,  W9,  W10, W11)
        CHUNK(3, W12, W13, W14, W15)
        CHUNK(4, W16, W17, W18, W19)
        CHUNK(5, W20, W21, W22, W23)
        CHUNK(6, W24, W25, W26, W27)
        CHUNK(7, W28, W29, W30, W31)
#undef CHUNK

        gates_part[half * 512 + j] = (a0 + a1) + (a2 + a3);
        __syncthreads();

        if (tid < HDIM) {
            float gi = sigm(gates_part[tid]            + gates_part[tid + 512]);
            float gf = sigm(gates_part[tid + 128]      + gates_part[tid + 640]);
            float gg = tanh_fast(gates_part[tid + 256] + gates_part[tid + 768]);
            float go = sigm(gates_part[tid + 384]      + gates_part[tid + 896]);
            c = fmaf(gf, c, gi * gg);
            float h = go * tanh_fast(c);
            *hw = (_Float16)h;

            float p = tanh_fast(h) * wout;
            #pragma unroll
            for (int off = 32; off > 0; off >>= 1)
                p += __shfl_xor(p, off, 64);
            if ((tid & 63) == 0) red_sh[tid >> 6] = p;
        }
        __syncthreads();

        if (tid == 0) out[t] = red_sh[0] + red_sh[1] + bout;
        xcur = xnext;
    }
}

extern "C" void kernel_launch(void* const* d_in, const int* in_sizes, int n_in,
                              void* d_out, int out_size, void* d_ws, size_t ws_size,
                              hipStream_t stream) {
    const float* x     = (const float*)d_in[0];
    const float* h0    = (const float*)d_in[1];
    const float* c0    = (const float*)d_in[2];
    const float* W_ih  = (const float*)d_in[3];
    const float* W_hh  = (const float*)d_in[4];
    const float* b_ih  = (const float*)d_in[5];
    const float* b_hh  = (const float*)d_in[6];
    const float* W_out = (const float*)d_in[7];
    const float* b_out = (const float*)d_in[8];

    const size_t need = (size_t)S_LEN * HDIM * sizeof(_Float16);  // 16 MiB
    if (ws_size >= need) {
        _Float16* h_hist = (_Float16*)d_ws;
        lstm_seq_mfma<<<dim3(1), dim3(512), 0, stream>>>(
            x, h0, c0, W_ih, W_hh, b_ih, b_hh, h_hist);
        out_proj<<<dim3(1024), dim3(256), 0, stream>>>(
            h_hist, W_out, b_out, (float*)d_out);
    } else {
        lstm_seq_full<<<dim3(1), dim3(1024), 0, stream>>>(
            x, h0, c0, W_ih, W_hh, b_ih, b_hh, W_out, b_out, (float*)d_out);
    }
}

// Round 2
// 39209.113 us; speedup vs baseline: 1.1905x; 1.0337x over previous
//
#include <hip/hip_runtime.h>

#define S_LEN 65536
#define HDIM 128

typedef _Float16 half2_t __attribute__((ext_vector_type(2)));
typedef _Float16 half8_t __attribute__((ext_vector_type(8)));
typedef float f32x4 __attribute__((ext_vector_type(4)));

__device__ __forceinline__ float sigm(float x) {
    return 1.0f / (1.0f + __expf(-x));
}
__device__ __forceinline__ float tanh_fast(float x) {
    return 2.0f / (1.0f + __expf(-2.0f * x)) - 1.0f;
}
__device__ __forceinline__ float dot2(half2_t a, half2_t b, float c) {
#if __has_builtin(__builtin_amdgcn_fdot2)
    return __builtin_amdgcn_fdot2(a, b, c, false);
#else
    return fmaf((float)a.x, (float)b.x, fmaf((float)a.y, (float)b.y, c));
#endif
}

// Raw workgroup barrier: drain LDS only (lgkmcnt), leave global loads/stores
// (x prefetch, h_hist) in flight across the barrier.
#define WG_BARRIER() do {                                         \
    asm volatile("s_waitcnt lgkmcnt(0)" ::: "memory");            \
    __builtin_amdgcn_s_barrier();                                 \
    asm volatile("" ::: "memory");                                \
} while (0)

// ================= Kernel 1: MFMA recurrence, 4 waves (1/SIMD) ============
// R8 post-mortem of R7: 8 waves = 2/SIMD, both siblings run the SAME
// barrier-locked serial chain -> they don't hide latency, they double VALU
// issue (~480cy/SIMD/step of redundant select/act/zero-init issue at 16/64
// lane utilization). Fix: 4 waves, 1/SIMD. Each wave owns h-slice
// [32w,32w+32) x 4 gates = 8 MFMA tiles, A-frags = 128 VGPR/lane
// (waves_per_eu(1,1): 512-reg budget, no spill). Per-SIMD VALU issue per
// step halves; no sibling contention; MFMA issue 16->32 (+80cy) is cheap.
// Extra trims: acc zero-init hoisted into pinned loop-invariant zf
// (kills 32 movs/step), h_hist pointer strength-reduced, xg fmas issued in
// the ds_read shadow.
// Layouts (verified): A[m=lane&15][k=(lane>>4)*8+j]; B mirrored;
// D col=lane&15, row=4*quad+reg.
__global__ __launch_bounds__(256)
__attribute__((amdgpu_waves_per_eu(1, 1)))
void lstm_seq_mfma(const float* __restrict__ x,
                   const float* __restrict__ h0,
                   const float* __restrict__ c0,
                   const float* __restrict__ W_ih,
                   const float* __restrict__ W_hh,
                   const float* __restrict__ b_ih,
                   const float* __restrict__ b_hh,
                   _Float16* __restrict__ h_hist)
{
    __shared__ __align__(16) _Float16 h_buf[2][HDIM];  // ping-pong h_t (f16)

    const int tid  = threadIdx.x;       // 0..255, 4 waves
    const int lane = tid & 63;
    const int w    = tid >> 6;          // wave id 0..3: h-slice [32w,32w+32)
    const int m    = lane & 15;         // A row within tile; also B/D col
    const int quad = lane >> 4;         // 0..3

    // ---- A fragments: tile (i,ti) = gate i rows of h[32w+16ti .. +16) ----
    // row = i*128 + 32*w + 16*ti + m ; 32 frags x 4 VGPR = 128 VGPR.
#define LOAD_AF(i, ti, cc) \
    half8_t af_##i##_##ti##_##cc; { \
        const float* s_ = W_hh + (size_t)((i) * 128 + w * 32 + 16 * (ti) + m) * HDIM \
                               + 32 * (cc) + 8 * quad; \
        af_##i##_##ti##_##cc = (half8_t){ \
            (_Float16)s_[0], (_Float16)s_[1], (_Float16)s_[2], (_Float16)s_[3], \
            (_Float16)s_[4], (_Float16)s_[5], (_Float16)s_[6], (_Float16)s_[7] }; \
        asm volatile("" : "+v"(af_##i##_##ti##_##cc)); }
    LOAD_AF(0,0,0) LOAD_AF(0,0,1) LOAD_AF(0,0,2) LOAD_AF(0,0,3)
    LOAD_AF(0,1,0) LOAD_AF(0,1,1) LOAD_AF(0,1,2) LOAD_AF(0,1,3)
    LOAD_AF(1,0,0) LOAD_AF(1,0,1) LOAD_AF(1,0,2) LOAD_AF(1,0,3)
    LOAD_AF(1,1,0) LOAD_AF(1,1,1) LOAD_AF(1,1,2) LOAD_AF(1,1,3)
    LOAD_AF(2,0,0) LOAD_AF(2,0,1) LOAD_AF(2,0,2) LOAD_AF(2,0,3)
    LOAD_AF(2,1,0) LOAD_AF(2,1,1) LOAD_AF(2,1,2) LOAD_AF(2,1,3)
    LOAD_AF(3,0,0) LOAD_AF(3,0,1) LOAD_AF(3,0,2) LOAD_AF(3,0,3)
    LOAD_AF(3,1,0) LOAD_AF(3,1,1) LOAD_AF(3,1,2) LOAD_AF(3,1,3)
#undef LOAD_AF

    // ---- Worker lanes: m<8, one h element each (32 per wave) ----
    // hidx = 32w + 16*ti + 4*quad + r with ti=(m>>2)&1, r=m&3.
    const bool worker = (m < 8);
    const int  hidx   = w * 32 + 16 * ((m >> 2) & 1) + 4 * quad + (m & 3);
    float wi00 = 0.f, wi01 = 0.f, bs0 = 0.f;
    float wi10 = 0.f, wi11 = 0.f, bs1 = 0.f;
    float wi20 = 0.f, wi21 = 0.f, bs2 = 0.f;
    float wi30 = 0.f, wi31 = 0.f, bs3 = 0.f;
    float c = 0.0f;
    if (worker) {
        const int r0 = hidx;
        const int r1 = hidx + 128;
        const int r2 = hidx + 256;
        const int r3 = hidx + 384;
        wi00 = W_ih[2 * r0]; wi01 = W_ih[2 * r0 + 1]; bs0 = b_ih[r0] + b_hh[r0];
        wi10 = W_ih[2 * r1]; wi11 = W_ih[2 * r1 + 1]; bs1 = b_ih[r1] + b_hh[r1];
        wi20 = W_ih[2 * r2]; wi21 = W_ih[2 * r2 + 1]; bs2 = b_ih[r2] + b_hh[r2];
        wi30 = W_ih[2 * r3]; wi31 = W_ih[2 * r3 + 1]; bs3 = b_ih[r3] + b_hh[r3];
        c = c0[hidx];
    }
    if (tid < HDIM) h_buf[0][tid] = (_Float16)h0[tid];
    __syncthreads();

    const float2* xp = (const float2*)x;
    float2 xcur = xp[0];                 // FIFO depth 2: covers L2 latency
    float2 xn1  = xp[1];

    const bool selod = (m & 1) != 0;
    const bool selhi = (m & 2) != 0;
    const bool selti = (m & 4) != 0;

    // Loop-invariant zero accumulator seed: first MFMA of each tile reads
    // this instead of freshly mov'd zeros (saves 32 v_mov per step).
    f32x4 zf = {0.f, 0.f, 0.f, 0.f};
    asm volatile("" : "+v"(zf));

    _Float16* hh = h_hist + hidx;        // worker store pointer (strength-red.)

#define MFMA_T(i, ti) \
    f32x4 a_##i##_##ti; \
    a_##i##_##ti = __builtin_amdgcn_mfma_f32_16x16x32_f16(af_##i##_##ti##_0, bf0, zf,           0, 0, 0); \
    a_##i##_##ti = __builtin_amdgcn_mfma_f32_16x16x32_f16(af_##i##_##ti##_1, bf1, a_##i##_##ti, 0, 0, 0); \
    a_##i##_##ti = __builtin_amdgcn_mfma_f32_16x16x32_f16(af_##i##_##ti##_2, bf2, a_##i##_##ti, 0, 0, 0); \
    a_##i##_##ti = __builtin_amdgcn_mfma_f32_16x16x32_f16(af_##i##_##ti##_3, bf3, a_##i##_##ti, 0, 0, 0);

    // Select gate value: reg r = m&3 from both halves, then ti = m&4.
#define GSEL(i, dst, xg_) { \
    float lA_ = selod ? a_##i##_0[1] : a_##i##_0[0]; \
    float hA_ = selod ? a_##i##_0[3] : a_##i##_0[2]; \
    float vA_ = selhi ? hA_ : lA_; \
    float lB_ = selod ? a_##i##_1[1] : a_##i##_1[0]; \
    float hB_ = selod ? a_##i##_1[3] : a_##i##_1[2]; \
    float vB_ = selhi ? hB_ : lB_; \
    dst = (selti ? vB_ : vA_) + xg_; }

#define STEP(T, RB, WB, OFF) { \
    /* B frags: all lanes read the same 4 lines (broadcast) */ \
    const half8_t* hb_ = (const half8_t*)(RB); \
    half8_t bf0 = hb_[quad]; \
    half8_t bf1 = hb_[4 + quad]; \
    half8_t bf2 = hb_[8 + quad]; \
    half8_t bf3 = hb_[12 + quad]; \
    int tn_ = (T) + 2; if (tn_ >= S_LEN) tn_ = S_LEN - 1; \
    float2 xnew_ = xp[tn_]; \
    /* xg fmas issue in the ds_read shadow */ \
    const float xg0 = fmaf(wi00, xcur.x, fmaf(wi01, xcur.y, bs0)); \
    const float xg1 = fmaf(wi10, xcur.x, fmaf(wi11, xcur.y, bs1)); \
    const float xg2 = fmaf(wi20, xcur.x, fmaf(wi21, xcur.y, bs2)); \
    const float xg3 = fmaf(wi30, xcur.x, fmaf(wi31, xcur.y, bs3)); \
    MFMA_T(0, 0) MFMA_T(0, 1) \
    MFMA_T(1, 0) MFMA_T(1, 1) \
    MFMA_T(2, 0) MFMA_T(2, 1) \
    MFMA_T(3, 0) MFMA_T(3, 1) \
    if (worker) { \
        float g0, g1, g2, g3; \
        GSEL(0, g0, xg0) \
        GSEL(1, g1, xg1) \
        GSEL(2, g2, xg2) \
        GSEL(3, g3, xg3) \
        const float gi = sigm(g0); \
        const float gf = sigm(g1); \
        const float gg = tanh_fast(g2); \
        const float go = sigm(g3); \
        c = fmaf(gf, c, gi * gg); \
        const float hv_ = go * tanh_fast(c); \
        const _Float16 hf_ = (_Float16)hv_; \
        (WB)[hidx] = hf_;                 /* feeds next step B-frags */ \
        hh[OFF] = hf_;                    /* h_hist, consumed by out_proj */ \
    } \
    xcur = xn1; xn1 = xnew_; \
    WG_BARRIER(); }

    #pragma unroll 1
    for (int t = 0; t < S_LEN; t += 2) {
        STEP(t,     h_buf[0], h_buf[1], 0)
        STEP(t + 1, h_buf[1], h_buf[0], HDIM)
        hh += 2 * HDIM;
    }
#undef STEP
#undef GSEL
#undef MFMA_T
}

// ================= Kernel 2: out[t] = tanh(h_t).W_out + b =================
__global__ __launch_bounds__(256)
void out_proj(const _Float16* __restrict__ h_hist,
              const float* __restrict__ W_out,
              const float* __restrict__ b_out,
              float* __restrict__ out)
{
    const int lane  = threadIdx.x & 63;
    const int gwave = (blockIdx.x * 256 + threadIdx.x) >> 6;
    const int nwave = (gridDim.x * 256) >> 6;

    const float wo0 = W_out[2 * lane + 0];
    const float wo1 = W_out[2 * lane + 1];
    const float bout = b_out[0];

    for (int t = gwave; t < S_LEN; t += nwave) {
        half2_t hv = ((const half2_t*)(h_hist + t * HDIM))[lane];
        float p = tanh_fast((float)hv.x) * wo0 + tanh_fast((float)hv.y) * wo1;
        #pragma unroll
        for (int off = 32; off > 0; off >>= 1)
            p += __shfl_xor(p, off, 64);
        if (lane == 0) out[t] = p + bout;
    }
}

// ================= Fallback: fused single kernel (ws too small) ===========
#define H_HI_OFF 144
__global__ __launch_bounds__(1024)
__attribute__((amdgpu_waves_per_eu(4, 4)))
void lstm_seq_full(const float* __restrict__ x,
                   const float* __restrict__ h0,
                   const float* __restrict__ c0,
                   const float* __restrict__ W_ih,
                   const float* __restrict__ W_hh,
                   const float* __restrict__ b_ih,
                   const float* __restrict__ b_hh,
                   const float* __restrict__ W_out,
                   const float* __restrict__ b_out,
                   float* __restrict__ out)
{
    __shared__ __align__(16) unsigned char h_raw[2 * H_HI_OFF];
    __shared__ float gates_part[2 * 512];
    __shared__ float red_sh[2];

    const int tid  = threadIdx.x;
    const int j    = tid >> 1;
    const int half = tid & 1;

    const float2* wr2 = (const float2*)(W_hh + j * HDIM + half * 64);
#define WDEF(i) half2_t W##i; { float2 t = wr2[i]; \
        W##i.x = (_Float16)t.x; W##i.y = (_Float16)t.y; } \
        asm volatile("" : "+v"(W##i));
    WDEF(0)  WDEF(1)  WDEF(2)  WDEF(3)  WDEF(4)  WDEF(5)  WDEF(6)  WDEF(7)
    WDEF(8)  WDEF(9)  WDEF(10) WDEF(11) WDEF(12) WDEF(13) WDEF(14) WDEF(15)
    WDEF(16) WDEF(17) WDEF(18) WDEF(19) WDEF(20) WDEF(21) WDEF(22) WDEF(23)
    WDEF(24) WDEF(25) WDEF(26) WDEF(27) WDEF(28) WDEF(29) WDEF(30) WDEF(31)
#undef WDEF

    float wih0 = 0.0f, wih1 = 0.0f, bias = 0.0f;
    if (half == 0) {
        wih0 = W_ih[2 * j + 0];
        wih1 = W_ih[2 * j + 1];
        bias = b_ih[j] + b_hh[j];
    }

    float c = 0.0f, wout = 0.0f;
    _Float16* hw = (_Float16*)(h_raw + ((tid < 64) ? 2 * tid
                                                   : H_HI_OFF + 2 * (tid - 64)));
    if (tid < HDIM) {
        c = c0[tid];
        wout = W_out[tid];
        *hw = (_Float16)h0[tid];
    }
    const float bout = b_out[0];
    __syncthreads();

    const float2* xp = (const float2*)x;
    float2 xcur = xp[0];
    const half8_t* hp = (const half8_t*)(h_raw + half * H_HI_OFF);

    #pragma unroll 1
    for (int t = 0; t < S_LEN; ++t) {
        const int tn = (t + 1 < S_LEN) ? (t + 1) : (S_LEN - 1);
        float2 xnext = xp[tn];

        float a0 = fmaf(wih0, xcur.x, fmaf(wih1, xcur.y, bias));
        float a1 = 0.0f, a2 = 0.0f, a3 = 0.0f;

#define CHUNK(cc, w0_, w1_, w2_, w3_) {                         \
        half8_t hv = hp[cc];                                    \
        half2_t p0 = { hv[0], hv[1] };                          \
        half2_t p1 = { hv[2], hv[3] };                          \
        half2_t p2 = { hv[4], hv[5] };                          \
        half2_t p3 = { hv[6], hv[7] };                          \
        a0 = dot2(w0_, p0, a0);                                 \
        a1 = dot2(w1_, p1, a1);                                 \
        a2 = dot2(w2_, p2, a2);                                 \
        a3 = dot2(w3_, p3, a3); }
        CHUNK(0, W0,  W1,  W2,  W3)
        CHUNK(1, W4,  W5,  W6,  W7)
        CHUNK(2, W8,  W9,  W10, W11)
        CHUNK(3, W12, W13, W14, W15)
        CHUNK(4, W16, W17, W18, W19)
        CHUNK(5, W20, W21, W22, W23)
        CHUNK(6, W24, W25, W26, W27)
        CHUNK(7, W28, W29, W30, W31)
#undef CHUNK

        gates_part[half * 512 + j] = (a0 + a1) + (a2 + a3);
        __syncthreads();

        if (tid < HDIM) {
            float gi = sigm(gates_part[tid]            + gates_part[tid + 512]);
            float gf = sigm(gates_part[tid + 128]      + gates_part[tid + 640]);
            float gg = tanh_fast(gates_part[tid + 256] + gates_part[tid + 768]);
            float go = sigm(gates_part[tid + 384]      + gates_part[tid + 896]);
            c = fmaf(gf, c, gi * gg);
            float h = go * tanh_fast(c);
            *hw = (_Float16)h;

            float p = tanh_fast(h) * wout;
            #pragma unroll
            for (int off = 32; off > 0; off >>= 1)
                p += __shfl_xor(p, off, 64);
            if ((tid & 63) == 0) red_sh[tid >> 6] = p;
        }
        __syncthreads();

        if (tid == 0) out[t] = red_sh[0] + red_sh[1] + bout;
        xcur = xnext;
    }
}

extern "C" void kernel_launch(void* const* d_in, const int* in_sizes, int n_in,
                              void* d_out, int out_size, void* d_ws, size_t ws_size,
                              hipStream_t stream) {
    const float* x     = (const float*)d_in[0];
    const float* h0    = (const float*)d_in[1];
    const float* c0    = (const float*)d_in[2];
    const float* W_ih  = (const float*)d_in[3];
    const float* W_hh  = (const float*)d_in[4];
    const float* b_ih  = (const float*)d_in[5];
    const float* b_hh  = (const float*)d_in[6];
    const float* W_out = (const float*)d_in[7];
    const float* b_out = (const float*)d_in[8];

    const size_t need = (size_t)S_LEN * HDIM * sizeof(_Float16);  // 16 MiB
    if (ws_size >= need) {
        _Float16* h_hist = (_Float16*)d_ws;
        lstm_seq_mfma<<<dim3(1), dim3(256), 0, stream>>>(
            x, h0, c0, W_ih, W_hh, b_ih, b_hh, h_hist);
        out_proj<<<dim3(1024), dim3(256), 0, stream>>>(
            h_hist, W_out, b_out, (float*)d_out);
    } else {
        lstm_seq_full<<<dim3(1), dim3(1024), 0, stream>>>(
            x, h0, c0, W_ih, W_hh, b_ih, b_hh, W_out, b_out, (float*)d_out);
    }
}